// Round 2
// baseline (548.580 us; speedup 1.0000x reference)
//
#include <hip/hip_runtime.h>

// B=64, N=8, H=768, FS=32, S=1024 — all tensors float32 (reference dtypes).
#define Hh 768
#define Nn 8
#define VSTRIDE 196   // 192 + 4 pad: makes GEMM b128 reads bank-conflict-free

// ============================================================
// Kernel 1: t[b,n,h] = LN2( lin_w @ LN1(token) + lin_b )  (f32 -> ws)
// one block per b; 256 threads = 8 rows x 32 lanes; 24 h per lane
// ============================================================
__global__ __launch_bounds__(256) void k_token(
    const float* __restrict__ token, const float* __restrict__ ln1w, const float* __restrict__ ln1b,
    const float* __restrict__ linw,  const float* __restrict__ linb,
    const float* __restrict__ ln2w,  const float* __restrict__ ln2b,
    float* __restrict__ t_ws)
{
  __shared__ float tn_s[Nn * Hh];   // 24 KB
  const int b = blockIdx.x, tid = threadIdx.x;
  const int n = tid >> 5, g = tid & 31;
  const int h0 = g * 24;

  float xv[24];
  {
    const float4* p = (const float4*)(token + ((size_t)b * Nn + n) * Hh + h0);
#pragma unroll
    for (int k = 0; k < 6; ++k) {
      float4 u = p[k];
      xv[k * 4 + 0] = u.x; xv[k * 4 + 1] = u.y; xv[k * 4 + 2] = u.z; xv[k * 4 + 3] = u.w;
    }
  }
  float s = 0.f, q = 0.f;
#pragma unroll
  for (int j = 0; j < 24; ++j) { s += xv[j]; q += xv[j] * xv[j]; }
#pragma unroll
  for (int m = 16; m; m >>= 1) { s += __shfl_xor(s, m, 64); q += __shfl_xor(q, m, 64); }
  float mu = s * (1.f / 768.f);
  float rs = rsqrtf(q * (1.f / 768.f) - mu * mu + 1e-5f);
  {
    const float4* pw = (const float4*)(ln1w + h0);
    const float4* pb = (const float4*)(ln1b + h0);
#pragma unroll
    for (int k = 0; k < 6; ++k) {
      float4 w = pw[k], bb = pb[k];
      tn_s[n * Hh + h0 + k * 4 + 0] = (xv[k * 4 + 0] - mu) * rs * w.x + bb.x;
      tn_s[n * Hh + h0 + k * 4 + 1] = (xv[k * 4 + 1] - mu) * rs * w.y + bb.y;
      tn_s[n * Hh + h0 + k * 4 + 2] = (xv[k * 4 + 2] - mu) * rs * w.z + bb.z;
      tn_s[n * Hh + h0 + k * 4 + 3] = (xv[k * 4 + 3] - mu) * rs * w.w + bb.w;
    }
  }
  __syncthreads();

  // linear over token dim: out row m == n; needs lin_w[n, 0..7]
  float lwf[8];
  {
    float4 a = ((const float4*)(linw + n * 8))[0];
    float4 c = ((const float4*)(linw + n * 8))[1];
    lwf[0] = a.x; lwf[1] = a.y; lwf[2] = a.z; lwf[3] = a.w;
    lwf[4] = c.x; lwf[5] = c.y; lwf[6] = c.z; lwf[7] = c.w;
  }
  const float lbf = linb[n];
  float tl[24];
#pragma unroll
  for (int j4 = 0; j4 < 6; ++j4) {
    float a0 = lbf, a1 = lbf, a2 = lbf, a3 = lbf;
#pragma unroll
    for (int k = 0; k < 8; ++k) {
      float4 tv = *(const float4*)&tn_s[k * Hh + h0 + j4 * 4];
      a0 += tv.x * lwf[k]; a1 += tv.y * lwf[k]; a2 += tv.z * lwf[k]; a3 += tv.w * lwf[k];
    }
    tl[j4 * 4 + 0] = a0; tl[j4 * 4 + 1] = a1; tl[j4 * 4 + 2] = a2; tl[j4 * 4 + 3] = a3;
  }
  s = 0.f; q = 0.f;
#pragma unroll
  for (int j = 0; j < 24; ++j) { s += tl[j]; q += tl[j] * tl[j]; }
#pragma unroll
  for (int m = 16; m; m >>= 1) { s += __shfl_xor(s, m, 64); q += __shfl_xor(q, m, 64); }
  float mu2 = s * (1.f / 768.f);
  float rs2 = rsqrtf(q * (1.f / 768.f) - mu2 * mu2 + 1e-5f);
  {
    const float4* pw = (const float4*)(ln2w + h0);
    const float4* pb = (const float4*)(ln2b + h0);
    float* op = t_ws + ((size_t)b * Nn + n) * Hh + h0;
#pragma unroll
    for (int k = 0; k < 6; ++k) {
      float4 w = pw[k], bb = pb[k];
      float4 o;
      o.x = (tl[k * 4 + 0] - mu2) * rs2 * w.x + bb.x;
      o.y = (tl[k * 4 + 1] - mu2) * rs2 * w.y + bb.y;
      o.z = (tl[k * 4 + 2] - mu2) * rs2 * w.z + bb.z;
      o.w = (tl[k * 4 + 3] - mu2) * rs2 * w.w + bb.w;
      ((float4*)op)[k] = o;
    }
  }
}

// ============================================================
// Kernel 2: per (b,x) tile of 32 spatial rows (y), f32:
//   per-h stats over y (var eps = featmap_size = 32.0), mix GEMM on raw
//   staged v via rescaled weights w = conv*rstd, sigmoid,
//   out[b, 32x+y, h] = sum_n t[b,n,h] * mix[n,y]
// LDS ~37 KB -> 4 blocks/CU
// ============================================================
__global__ __launch_bounds__(256, 4) void k_fuse(
    const float* __restrict__ ori, const float* __restrict__ lnow, const float* __restrict__ lnob,
    const float* __restrict__ convw, const float* __restrict__ t_ws, float* __restrict__ outp)
{
  __shared__ float v_s[32 * VSTRIDE];  // 24.5 KB quarter-tile: [y][h_local(192)+pad]
  __shared__ float mu_s[Hh];           // 3 KB
  __shared__ float rstd_s[Hh];         // 3 KB
  __shared__ float mixp[32 * 40];      // 5 KB   [y][g*8+n]
  __shared__ float c1p_s[32], c2p_s[32];
  __shared__ float mix_s[32 * 8];      // 1 KB   [y][n]

  const int bx = blockIdx.x;
  const int b = bx >> 5, x = bx & 31;
  const int tid = threadIdx.x;
  const float* orib = ori + ((size_t)b * 1024 + x * 32) * Hh;

  const int n = tid & 7, g = (tid >> 3) & 3, ys = tid >> 5;
  float acc0 = 0.f, acc1 = 0.f, acc2 = 0.f, acc3 = 0.f, c1p = 0.f, c2p = 0.f;

  for (int q = 0; q < 4; ++q) {
    // ---- stage quarter tile: 32 rows x 192 f32, 48 x 16B chunks/row ----
#pragma unroll
    for (int k = 0; k < 6; ++k) {
      int c = tid + k * 256;
      int y = c / 48, r = c - y * 48;
      float4 u = *(const float4*)(orib + (size_t)y * Hh + q * 192 + r * 4);
      *(float4*)&v_s[y * VSTRIDE + r * 4] = u;
    }
    __syncthreads();
    // ---- stats per h over y (biased var, eps = 32.0) ----
    if (tid < 192) {
      float s = 0.f, qq = 0.f;
#pragma unroll 8
      for (int y = 0; y < 32; ++y) {
        float f = v_s[y * VSTRIDE + tid];
        s += f; qq += f * f;
      }
      int h = q * 192 + tid;
      float m = s * (1.f / 32.f);
      mu_s[h] = m;
      rstd_s[h] = rsqrtf(qq * (1.f / 32.f) - m * m + 32.0f);
    }
    __syncthreads();
    // ---- mix GEMM partial: thread (n,g,ys): 48 h x 4 y per quarter.
    //      interleaved h map (jc*16 + g*4) => wave's 8 b128 addrs start at
    //      banks {0,4,..,28} (VSTRIDE=196 shifts ys by 16) => conflict-free.
    for (int jc = 0; jc < 12; ++jc) {
      int hl = jc * 16 + g * 4;
      int h = q * 192 + hl;
      float4 cw = *(const float4*)(convw + n * Hh + h);
      float4 rv = *(const float4*)&rstd_s[h];
      float4 mv = *(const float4*)&mu_s[h];
      float w0 = cw.x * rv.x, w1 = cw.y * rv.y, w2 = cw.z * rv.z, w3 = cw.w * rv.w;
      c1p += w0 * mv.x + w1 * mv.y + w2 * mv.z + w3 * mv.w;
      c2p += cw.x + cw.y + cw.z + cw.w;
      int base = (ys * 4) * VSTRIDE + hl;
      {
        float4 vv = *(const float4*)&v_s[base];
        acc0 += w0 * vv.x + w1 * vv.y + w2 * vv.z + w3 * vv.w;
      }
      {
        float4 vv = *(const float4*)&v_s[base + VSTRIDE];
        acc1 += w0 * vv.x + w1 * vv.y + w2 * vv.z + w3 * vv.w;
      }
      {
        float4 vv = *(const float4*)&v_s[base + 2 * VSTRIDE];
        acc2 += w0 * vv.x + w1 * vv.y + w2 * vv.z + w3 * vv.w;
      }
      {
        float4 vv = *(const float4*)&v_s[base + 3 * VSTRIDE];
        acc3 += w0 * vv.x + w1 * vv.y + w2 * vv.z + w3 * vv.w;
      }
    }
    __syncthreads();   // before restaging v_s
  }

  mixp[(ys * 4 + 0) * 40 + g * 8 + n] = acc0;
  mixp[(ys * 4 + 1) * 40 + g * 8 + n] = acc1;
  mixp[(ys * 4 + 2) * 40 + g * 8 + n] = acc2;
  mixp[(ys * 4 + 3) * 40 + g * 8 + n] = acc3;
  if (ys == 0) { c1p_s[g * 8 + n] = c1p; c2p_s[g * 8 + n] = c2p; }
  __syncthreads();

  // ---- reduce over g, apply lno affine + sigmoid ----
  {
    int y = tid >> 3, nn = tid & 7;
    float m1 = mixp[y * 40 + nn] + mixp[y * 40 + 8 + nn] +
               mixp[y * 40 + 16 + nn] + mixp[y * 40 + 24 + nn];
    float c1 = c1p_s[nn] + c1p_s[8 + nn] + c1p_s[16 + nn] + c1p_s[24 + nn];
    float c2 = c2p_s[nn] + c2p_s[8 + nn] + c2p_s[16 + nn] + c2p_s[24 + nn];
    float aa = lnow[y] * (m1 - c1) + lnob[y] * c2;
    mix_s[y * 8 + nn] = 1.f / (1.f + __expf(-aa));
  }
  __syncthreads();

  // ---- output: thread owns 4 h-channels across all y; t in registers ----
  if (tid < 192) {
    const int h0 = tid * 4;
    float tr[8][4];
#pragma unroll
    for (int k = 0; k < 8; ++k) {
      float4 tv = *(const float4*)&t_ws[((size_t)b * Nn + k) * Hh + h0];
      tr[k][0] = tv.x; tr[k][1] = tv.y; tr[k][2] = tv.z; tr[k][3] = tv.w;
    }
    float* ob = outp + ((size_t)b * 1024 + x * 32) * Hh + h0;
#pragma unroll 4
    for (int y = 0; y < 32; ++y) {
      float4 mA = *(const float4*)&mix_s[y * 8];
      float4 mB = *(const float4*)&mix_s[y * 8 + 4];
      float4 o;
      o.x = tr[0][0] * mA.x + tr[1][0] * mA.y + tr[2][0] * mA.z + tr[3][0] * mA.w
          + tr[4][0] * mB.x + tr[5][0] * mB.y + tr[6][0] * mB.z + tr[7][0] * mB.w;
      o.y = tr[0][1] * mA.x + tr[1][1] * mA.y + tr[2][1] * mA.z + tr[3][1] * mA.w
          + tr[4][1] * mB.x + tr[5][1] * mB.y + tr[6][1] * mB.z + tr[7][1] * mB.w;
      o.z = tr[0][2] * mA.x + tr[1][2] * mA.y + tr[2][2] * mA.z + tr[3][2] * mA.w
          + tr[4][2] * mB.x + tr[5][2] * mB.y + tr[6][2] * mB.z + tr[7][2] * mB.w;
      o.w = tr[0][3] * mA.x + tr[1][3] * mA.y + tr[2][3] * mA.z + tr[3][3] * mA.w
          + tr[4][3] * mB.x + tr[5][3] * mB.y + tr[6][3] * mB.z + tr[7][3] * mB.w;
      *(float4*)(ob + (size_t)y * Hh) = o;
    }
  }
}

extern "C" void kernel_launch(void* const* d_in, const int* in_sizes, int n_in,
                              void* d_out, int out_size, void* d_ws, size_t ws_size,
                              hipStream_t stream) {
  const float* token = (const float*)d_in[0];
  const float* ori   = (const float*)d_in[1];
  const float* ln1w  = (const float*)d_in[2];
  const float* ln1b  = (const float*)d_in[3];
  const float* linw  = (const float*)d_in[4];
  const float* linb  = (const float*)d_in[5];
  const float* ln2w  = (const float*)d_in[6];
  const float* ln2b  = (const float*)d_in[7];
  const float* lnow  = (const float*)d_in[8];
  const float* lnob  = (const float*)d_in[9];
  const float* convw = (const float*)d_in[10];
  float* t_ws = (float*)d_ws;             // 64*8*768 f32 = 1.5 MB
  float* outp = (float*)d_out;

  k_token<<<64, 256, 0, stream>>>(token, ln1w, ln1b, linw, linb, ln2w, ln2b, t_ws);
  k_fuse<<<2048, 256, 0, stream>>>(ori, lnow, lnob, convw, t_ws, outp);
}